// Round 15
// baseline (530.129 us; speedup 1.0000x reference)
//
#include <hip/hip_runtime.h>
#include <math.h>

typedef __attribute__((ext_vector_type(8))) short short8;
typedef __attribute__((ext_vector_type(4))) float f32x4;

typedef const __attribute__((address_space(1))) void gv_t;
typedef __attribute__((address_space(3))) void lv_t;

__device__ __forceinline__ float b2f(short u) {
  union { unsigned int i; float f; } c; c.i = ((unsigned int)(unsigned short)u) << 16; return c.f;
}
__device__ __forceinline__ short f2b(float f) {
  union { float f; unsigned int i; } c; c.f = f;
  unsigned int r = c.i + 0x7FFFu + ((c.i >> 16) & 1u);
  return (short)(r >> 16);
}
__device__ __forceinline__ void glds(const short* g, short* l) {
  __builtin_amdgcn_global_load_lds((gv_t*)g, (lv_t*)l, 16, 0, 0);
}

// ---------------- prep: LDS-tiled transposes + gbias + slots init + features->bf16 ----------------
// blocks: [0,1392) transpose tiles | [1392,1400) gbias | [1400,2168) slots init |
// [2168,20600) features fp32->bf16

__global__ __launch_bounds__(256) void k_prep(
    const float* __restrict__ w_in, const float* __restrict__ wk, const float* __restrict__ wv,
    const float* __restrict__ wq, const float* __restrict__ wih, const float* __restrict__ whh,
    const float* __restrict__ bih, const float* __restrict__ bhh,
    const float* __restrict__ w1, const float* __restrict__ w2, const float* __restrict__ sl1,
    const float* __restrict__ mu, const float* __restrict__ lsig, const float* __restrict__ noise,
    const float* __restrict__ features,
    short* __restrict__ Bt1, short* __restrict__ Btkv, short* __restrict__ wq_t,
    short* __restrict__ wgru, float* __restrict__ gbias,
    short* __restrict__ w1_t, short* __restrict__ w2_t, short* __restrict__ sl1_t,
    float* __restrict__ slots, short* __restrict__ gruA, short* __restrict__ Abf)
{
  int blk = blockIdx.x, t = threadIdx.x;
  if (blk >= 2168) {           // features fp32 -> bf16, 8 elems/thread, coalesced
    int idx = (blk-2168)*256 + t;
    const float4* p = (const float4*)(features + (size_t)idx * 8);
    float4 a = p[0], b = p[1];
    short8 r;
    r[0]=f2b(a.x); r[1]=f2b(a.y); r[2]=f2b(a.z); r[3]=f2b(a.w);
    r[4]=f2b(b.x); r[5]=f2b(b.y); r[6]=f2b(b.z); r[7]=f2b(b.w);
    *(short8*)(Abf + (size_t)idx*8) = r;
  } else if (blk < 1392) {
    __shared__ float tile[64][68];
    int id = blk;
    const float* src = nullptr; short* dst; int Kd, n0, k0, sld = 0, sr0 = 0, sc0 = 0;
    if (id < 144) {            // w_in (1152x512) -> Bt1 (512x1152)
      dst = Bt1; Kd = 1152; n0 = (id/18)*64; k0 = (id%18)*64;
      src = w_in; sld = 512; sr0 = k0; sc0 = n0;
    } else if (id < 272) {     // [wk|wv] -> Btkv (1024x512)
      id -= 144; dst = Btkv; Kd = 512; n0 = (id/8)*64; k0 = (id%8)*64;
      src = (n0 < 512) ? wk : wv; sld = 512; sr0 = k0; sc0 = n0 & 511;
    } else if (id < 336) {     // wq (512x512) -> wq_t
      id -= 272; dst = wq_t; Kd = 512; n0 = (id/8)*64; k0 = (id%8)*64;
      src = wq; sld = 512; sr0 = k0; sc0 = n0;
    } else if (id < 848) {     // combined GRU (2048x1024): [r|z|xn|hn]
      id -= 336; dst = wgru; Kd = 1024; n0 = (id/16)*64; k0 = (id%16)*64;
      int g = n0 >> 9, c0 = n0 & 511; bool hi = (k0 >= 512);
      sld = 1536; sr0 = hi ? k0 - 512 : k0;
      if (g == 0)      { src = hi ? whh : wih; sc0 = c0; }
      else if (g == 1) { src = hi ? whh : wih; sc0 = 512 + c0; }
      else if (g == 2) { src = hi ? nullptr : wih; sc0 = 1024 + c0; }
      else             { src = hi ? whh : nullptr; sc0 = 1024 + c0; }
    } else if (id < 1104) {    // ffn_w1 (512x2048) -> w1_t (2048x512)
      id -= 848; dst = w1_t; Kd = 512; n0 = (id/8)*64; k0 = (id%8)*64;
      src = w1; sld = 2048; sr0 = k0; sc0 = n0;
    } else if (id < 1360) {    // ffn_w2 (2048x512) -> w2_t (512x2048)
      id -= 1104; dst = w2_t; Kd = 2048; n0 = (id/32)*64; k0 = (id%32)*64;
      src = w2; sld = 512; sr0 = k0; sc0 = n0;
    } else {                   // sel_w1 (512x256) -> sl1_t (256x512)
      id -= 1360; dst = sl1_t; Kd = 512; n0 = (id/8)*64; k0 = (id%8)*64;
      src = sl1; sld = 256; sr0 = k0; sc0 = n0;
    }
    if (src) {
      #pragma unroll
      for (int i = 0; i < 4; ++i) {
        int kk = (t >> 4) + i*16, nn = (t & 15) * 4;
        *(float4*)&tile[kk][nn] = *(const float4*)(src + (size_t)(sr0+kk)*sld + sc0 + nn);
      }
    } else {
      #pragma unroll
      for (int i = 0; i < 4; ++i) {
        int kk = (t >> 4) + i*16, nn = (t & 15) * 4;
        tile[kk][nn] = 0.f; tile[kk][nn+1] = 0.f; tile[kk][nn+2] = 0.f; tile[kk][nn+3] = 0.f;
      }
    }
    __syncthreads();
    #pragma unroll
    for (int i = 0; i < 2; ++i) {
      int c = i*256 + t;
      int row = c >> 3, off = (c & 7) * 8;
      short8 o;
      #pragma unroll
      for (int e = 0; e < 8; ++e) o[e] = f2b(tile[off+e][row]);
      *(short8*)(dst + (size_t)(n0+row)*Kd + k0 + off) = o;
    }
  } else if (blk < 1400) {     // combined GRU bias (2048)
    int n = (blk-1392)*256 + t;
    int g = n >> 9;
    float v;
    if (g <= 1)      v = bih[n] + bhh[n];
    else if (g == 2) v = bih[n];
    else             v = bhh[1024 + (n - 1536)];
    gbias[n] = v;
  } else {                     // slots init (fp32 + bf16 into gruA 2nd half)
    int idx = (blk-1400)*256 + t;
    int sd = idx % 6144;
    float v = mu[sd] + __expf(lsig[sd]) * noise[idx];
    slots[idx] = v;
    int row = idx >> 9, c = idx & 511;
    gruA[(size_t)row*1024 + 512 + c] = f2b(v);
  }
}

// ---------------- big-GEMM bf16: dbuf + counted-vmcnt pipeline (round-6 proven) ----------------

__global__ __launch_bounds__(256) void gemm_p(
    const short* __restrict__ A, const short* __restrict__ Bt,
    const float* __restrict__ bias, short* __restrict__ Cb,
    int N, int K, int lda, int ldb)
{
  __shared__ short As[2][128*64];
  __shared__ short Bs[2][128*64];
  const int t = threadIdx.x;
  const int lane = t & 63, wave = t >> 6;

  const int nwg = gridDim.x, gridX = N >> 7, orig = blockIdx.x;
  const int q = nwg >> 3, r = nwg & 7, xcd = orig & 7, base = orig >> 3;
  const int wgid = (xcd < r ? xcd*(q+1) : r*(q+1) + (xcd - r)*q) + base;
  const int bx = wgid % gridX, by = wgid / gridX;

  const int rowBase = by * 128, colBase = bx * 128;
  const int wm = (wave >> 1) * 64, wn = (wave & 1) * 64;
  const int fr = lane & 15, kcf = lane >> 4;
  f32x4 acc[4][4] = {};

  int srow[4], scol[4];
  #pragma unroll
  for (int i = 0; i < 4; ++i) {
    int c = i*256 + t;
    srow[i] = c >> 3;
    scol[i] = ((c & 7) ^ (srow[i] & 7)) * 8;
  }

  const int nsteps = K >> 6;
  auto STAGE = [&](int step, int buf) {
    int kb = step * 64;
    #pragma unroll
    for (int i = 0; i < 4; ++i) {
      int c = i*256 + t;
      glds(A + (size_t)(rowBase + srow[i])*lda + kb + scol[i], As[buf] + c*8);
      glds(Bt + (size_t)(colBase + srow[i])*ldb + kb + scol[i], Bs[buf] + c*8);
    }
  };

  STAGE(0, 0);
  if (nsteps > 1) { STAGE(1, 1); asm volatile("s_waitcnt vmcnt(8)" ::: "memory"); }
  else            {              asm volatile("s_waitcnt vmcnt(0)" ::: "memory"); }
  __builtin_amdgcn_sched_barrier(0);
  __builtin_amdgcn_s_barrier();
  __builtin_amdgcn_sched_barrier(0);

  for (int tt = 0; tt < nsteps; ++tt) {
    const int cur = tt & 1;
    short8 af[2][4], bf[2][4];
    #pragma unroll
    for (int ks = 0; ks < 2; ++ks) {
      int kc = ks*4 + kcf;
      #pragma unroll
      for (int m = 0; m < 4; ++m) {
        int rowa = wm + m*16 + fr;
        af[ks][m] = *(const short8*)(As[cur] + rowa*64 + (kc ^ (rowa & 7))*8);
        int rowb = wn + m*16 + fr;
        bf[ks][m] = *(const short8*)(Bs[cur] + rowb*64 + (kc ^ (rowb & 7))*8);
      }
    }
    asm volatile("s_waitcnt lgkmcnt(0)" ::: "memory");
    __builtin_amdgcn_sched_barrier(0);
    __builtin_amdgcn_s_barrier();
    __builtin_amdgcn_sched_barrier(0);
    if (tt + 2 < nsteps) STAGE(tt + 2, cur);
    #pragma unroll
    for (int ks = 0; ks < 2; ++ks)
      #pragma unroll
      for (int m = 0; m < 4; ++m)
        #pragma unroll
        for (int n = 0; n < 4; ++n)
          acc[m][n] = __builtin_amdgcn_mfma_f32_16x16x32_bf16(af[ks][m], bf[ks][n], acc[m][n], 0, 0, 0);
    if (tt + 1 < nsteps) {
      if (tt + 2 < nsteps) asm volatile("s_waitcnt vmcnt(8)" ::: "memory");
      else                 asm volatile("s_waitcnt vmcnt(0)" ::: "memory");
      __builtin_amdgcn_sched_barrier(0);
      __builtin_amdgcn_s_barrier();
      __builtin_amdgcn_sched_barrier(0);
    }
  }

  const int cr = (lane >> 4) * 4, cc2 = lane & 15;
  #pragma unroll
  for (int m = 0; m < 4; ++m)
    #pragma unroll
    for (int n = 0; n < 4; ++n) {
      int col = colBase + wn + n*16 + cc2;
      float bv = bias ? bias[col] : 0.f;
      #pragma unroll
      for (int j = 0; j < 4; ++j) {
        int row = rowBase + wm + m*16 + cr + j;
        Cb[(size_t)row*N + col] = f2b(acc[m][n][j] + bv);
      }
    }
}

// ---------------- small-GEMM: dbuf counted-vmcnt pipeline, split-K capable ----------------

template<int ACT, bool OUTBF, bool SPLITK>
__global__ __launch_bounds__(256) void gemm_t(
    const short* __restrict__ A, const short* __restrict__ Bt,
    const float* __restrict__ bias,
    float* __restrict__ Cf, short* __restrict__ Cb,
    int N, int Kp, int lda, int ldb, int ldf, int ldcb, int cboff, int skstride)
{
  __shared__ short As[2][128*64];
  __shared__ short Bs[2][128*64];
  const int t = threadIdx.x;
  const int lane = t & 63, wave = t >> 6;

  const int nwg = gridDim.x, gridX = N >> 7, orig = blockIdx.x;
  const int q = nwg >> 3, r = nwg & 7, xcd = orig & 7, base = orig >> 3;
  const int wgid = (xcd < r ? xcd*(q+1) : r*(q+1) + (xcd - r)*q) + base;
  const int bx = wgid % gridX, by = wgid / gridX;

  const int rowBase = by * 128, colBase = bx * 128;
  const size_t koff = (size_t)blockIdx.y * Kp;
  const int wm = (wave >> 1) * 64, wn = (wave & 1) * 64;
  const int fr = lane & 15, kcf = lane >> 4;
  f32x4 acc[4][4] = {};

  int srow[4], scol[4];
  #pragma unroll
  for (int i = 0; i < 4; ++i) {
    int c = i*256 + t;
    srow[i] = c >> 3;
    scol[i] = ((c & 7) ^ (srow[i] & 7)) * 8;
  }

  const int nsteps = Kp >> 6;
  auto STAGE = [&](int step, int buf) {
    int kb = step * 64;
    #pragma unroll
    for (int i = 0; i < 4; ++i) {
      int c = i*256 + t;
      glds(A + (size_t)(rowBase + srow[i])*lda + koff + kb + scol[i], As[buf] + c*8);
      glds(Bt + (size_t)(colBase + srow[i])*ldb + koff + kb + scol[i], Bs[buf] + c*8);
    }
  };

  STAGE(0, 0);
  if (nsteps > 1) { STAGE(1, 1); asm volatile("s_waitcnt vmcnt(8)" ::: "memory"); }
  else            {              asm volatile("s_waitcnt vmcnt(0)" ::: "memory"); }
  __builtin_amdgcn_sched_barrier(0);
  __builtin_amdgcn_s_barrier();
  __builtin_amdgcn_sched_barrier(0);

  for (int tt = 0; tt < nsteps; ++tt) {
    const int cur = tt & 1;
    short8 af[2][4], bf[2][4];
    #pragma unroll
    for (int ks = 0; ks < 2; ++ks) {
      int kc = ks*4 + kcf;
      #pragma unroll
      for (int m = 0; m < 4; ++m) {
        int rowa = wm + m*16 + fr;
        af[ks][m] = *(const short8*)(As[cur] + rowa*64 + (kc ^ (rowa & 7))*8);
        int rowb = wn + m*16 + fr;
        bf[ks][m] = *(const short8*)(Bs[cur] + rowb*64 + (kc ^ (rowb & 7))*8);
      }
    }
    asm volatile("s_waitcnt lgkmcnt(0)" ::: "memory");
    __builtin_amdgcn_sched_barrier(0);
    __builtin_amdgcn_s_barrier();
    __builtin_amdgcn_sched_barrier(0);
    if (tt + 2 < nsteps) STAGE(tt + 2, cur);
    #pragma unroll
    for (int ks = 0; ks < 2; ++ks)
      #pragma unroll
      for (int m = 0; m < 4; ++m)
        #pragma unroll
        for (int n = 0; n < 4; ++n)
          acc[m][n] = __builtin_amdgcn_mfma_f32_16x16x32_bf16(af[ks][m], bf[ks][n], acc[m][n], 0, 0, 0);
    if (tt + 1 < nsteps) {
      if (tt + 2 < nsteps) asm volatile("s_waitcnt vmcnt(8)" ::: "memory");
      else                 asm volatile("s_waitcnt vmcnt(0)" ::: "memory");
      __builtin_amdgcn_sched_barrier(0);
      __builtin_amdgcn_s_barrier();
      __builtin_amdgcn_sched_barrier(0);
    }
  }

  const int cr = (lane >> 4) * 4, cc2 = lane & 15;
  if (SPLITK) {
    float* dst = Cf + (size_t)blockIdx.y * skstride;
    #pragma unroll
    for (int m = 0; m < 4; ++m)
      #pragma unroll
      for (int n = 0; n < 4; ++n) {
        int col = colBase + wn + n*16 + cc2;
        #pragma unroll
        for (int j = 0; j < 4; ++j) {
          int row = rowBase + wm + m*16 + cr + j;
          dst[(size_t)row * ldf + col] = acc[m][n][j];
        }
      }
  } else {
    #pragma unroll
    for (int m = 0; m < 4; ++m)
      #pragma unroll
      for (int n = 0; n < 4; ++n) {
        int col = colBase + wn + n*16 + cc2;
        float bv = bias ? bias[col] : 0.f;
        #pragma unroll
        for (int j = 0; j < 4; ++j) {
          int row = rowBase + wm + m*16 + cr + j;
          float v = acc[m][n][j] + bv;
          if (ACT == 1) v = 0.5f*v*(1.f + erff(v*0.70710678118f));
          else if (ACT == 2) v = fmaxf(v, 0.f);
          if (OUTBF) Cb[(size_t)row*ldcb + cboff + col] = f2b(v);
          else Cf[(size_t)row*ldf + col] = v;
        }
      }
  }
}

// ---------------- GRU reduce (2 partials) + combine + fused ffn-LN (1 wave/block) ----------------

__global__ __launch_bounds__(64) void k_gruln(const float* __restrict__ p, const float* __restrict__ gbias,
    float* __restrict__ slots, short* __restrict__ fln,
    const float* __restrict__ g, const float* __restrict__ bb)
{
  int lane = threadIdx.x;
  int row = blockIdx.x;                  // 384 blocks
  int c = lane * 8;
  float g0[8], g1[8], g2[8], g3[8];
  *(float4*)g0     = *(const float4*)(gbias + c);
  *(float4*)(g0+4) = *(const float4*)(gbias + c + 4);
  *(float4*)g1     = *(const float4*)(gbias + 512 + c);
  *(float4*)(g1+4) = *(const float4*)(gbias + 512 + c + 4);
  *(float4*)g2     = *(const float4*)(gbias + 1024 + c);
  *(float4*)(g2+4) = *(const float4*)(gbias + 1024 + c + 4);
  *(float4*)g3     = *(const float4*)(gbias + 1536 + c);
  *(float4*)(g3+4) = *(const float4*)(gbias + 1536 + c + 4);
  const float* base = p + (size_t)row*2048 + c;
  #pragma unroll
  for (int s = 0; s < 2; ++s) {
    const float* qq = base + (size_t)s*786432;
    #pragma unroll
    for (int gi = 0; gi < 4; ++gi) {
      float* dst = (gi == 0) ? g0 : (gi == 1) ? g1 : (gi == 2) ? g2 : g3;
      float4 a = *(const float4*)(qq + gi*512), b4 = *(const float4*)(qq + gi*512 + 4);
      dst[0]+=a.x; dst[1]+=a.y; dst[2]+=a.z; dst[3]+=a.w;
      dst[4]+=b4.x; dst[5]+=b4.y; dst[6]+=b4.z; dst[7]+=b4.w;
    }
  }
  float hold[8], v[8];
  *(float4*)hold     = *(const float4*)(slots + (size_t)row*512 + c);
  *(float4*)(hold+4) = *(const float4*)(slots + (size_t)row*512 + c + 4);
  #pragma unroll
  for (int e = 0; e < 8; ++e) {
    float r = 1.f/(1.f+__expf(-g0[e]));
    float z = 1.f/(1.f+__expf(-g1[e]));
    float n = tanhf(g2[e] + r*g3[e]);
    v[e] = (1.f-z)*n + z*hold[e];
  }
  *(float4*)(slots + (size_t)row*512 + c)     = *(float4*)v;
  *(float4*)(slots + (size_t)row*512 + c + 4) = *(float4*)(v+4);
  float s1 = 0.f, s2 = 0.f;
  #pragma unroll
  for (int e = 0; e < 8; ++e) { s1 += v[e]; s2 += v[e]*v[e]; }
  #pragma unroll
  for (int m = 1; m < 64; m <<= 1) { s1 += __shfl_xor(s1, m, 64); s2 += __shfl_xor(s2, m, 64); }
  float mean = s1 * (1.f/512.f);
  float rs = rsqrtf(s2*(1.f/512.f) - mean*mean + 1e-5f);
  short8 o;
  #pragma unroll
  for (int e = 0; e < 8; ++e) o[e] = f2b((v[e]-mean)*rs*g[c+e] + bb[c+e]);
  *(short8*)(fln + (size_t)row*512 + c) = o;
}

// ---------------- ffn2 reduce (4 partials) + residual + fused nslots-LN (1 wave/block) ----------------

__global__ __launch_bounds__(64) void k_ffn2redln(const float* __restrict__ p, const float* __restrict__ b2,
    float* __restrict__ slots, short* __restrict__ gruA, short* __restrict__ sn,
    const float* __restrict__ g, const float* __restrict__ bb)
{
  int lane = threadIdx.x;
  int row = blockIdx.x;                  // 384 blocks
  int c = lane * 8;
  size_t base = (size_t)row*512 + c;
  float v[8];
  *(float4*)v     = *(const float4*)(slots + base);
  *(float4*)(v+4) = *(const float4*)(slots + base + 4);
  #pragma unroll
  for (int e = 0; e < 8; ++e) v[e] += b2[c+e];
  #pragma unroll
  for (int s = 0; s < 4; ++s) {
    const float* qq = p + (size_t)s*196608 + base;
    float4 a = *(const float4*)qq, b4 = *(const float4*)(qq+4);
    v[0]+=a.x; v[1]+=a.y; v[2]+=a.z; v[3]+=a.w;
    v[4]+=b4.x; v[5]+=b4.y; v[6]+=b4.z; v[7]+=b4.w;
  }
  *(float4*)(slots + base)     = *(float4*)v;
  *(float4*)(slots + base + 4) = *(float4*)(v+4);
  short8 o;
  #pragma unroll
  for (int e = 0; e < 8; ++e) o[e] = f2b(v[e]);
  *(short8*)(gruA + (size_t)row*1024 + 512 + c) = o;
  float s1 = 0.f, s2 = 0.f;
  #pragma unroll
  for (int e = 0; e < 8; ++e) { s1 += v[e]; s2 += v[e]*v[e]; }
  #pragma unroll
  for (int m = 1; m < 64; m <<= 1) { s1 += __shfl_xor(s1, m, 64); s2 += __shfl_xor(s2, m, 64); }
  float mean = s1 * (1.f/512.f);
  float rs = rsqrtf(s2*(1.f/512.f) - mean*mean + 1e-5f);
  short8 o2;
  #pragma unroll
  for (int e = 0; e < 8; ++e) o2[e] = f2b((v[e]-mean)*rs*g[c+e] + bb[c+e]);
  *(short8*)(sn + base) = o2;
}

// ---------------- double layernorm: inp = LN2(LN1(y)), bf16 in/out, wave per row ----------------

__global__ __launch_bounds__(256) void k_ln2(const short* __restrict__ y, short* __restrict__ inp,
    const float* __restrict__ g1, const float* __restrict__ b1,
    const float* __restrict__ g2, const float* __restrict__ b2)
{
  int t = threadIdx.x, lane = t & 63;
  int row = blockIdx.x * 4 + (t >> 6);
  const short8 raw = *(const short8*)(y + (size_t)row*512 + lane*8);
  float x[8];
  #pragma unroll
  for (int e = 0; e < 8; ++e) x[e] = b2f(raw[e]);
  float s = 0.f, ss = 0.f;
  #pragma unroll
  for (int e = 0; e < 8; ++e) { s += x[e]; ss += x[e]*x[e]; }
  #pragma unroll
  for (int m = 1; m < 64; m <<= 1) { s += __shfl_xor(s, m, 64); ss += __shfl_xor(ss, m, 64); }
  float mean = s * (1.f/512.f);
  float rs = rsqrtf(ss*(1.f/512.f) - mean*mean + 1e-5f);
  int c = lane * 8;
  #pragma unroll
  for (int e = 0; e < 8; ++e) x[e] = (x[e]-mean)*rs*g1[c+e] + b1[c+e];
  s = 0.f; ss = 0.f;
  #pragma unroll
  for (int e = 0; e < 8; ++e) { s += x[e]; ss += x[e]*x[e]; }
  #pragma unroll
  for (int m = 1; m < 64; m <<= 1) { s += __shfl_xor(s, m, 64); ss += __shfl_xor(ss, m, 64); }
  float mean2 = s * (1.f/512.f);
  float rs2 = rsqrtf(ss*(1.f/512.f) - mean2*mean2 + 1e-5f);
  short8 o;
  #pragma unroll
  for (int e = 0; e < 8; ++e) o[e] = f2b((x[e]-mean2)*rs2*g2[c+e] + b2[c+e]);
  *(short8*)(inp + (size_t)row*512 + lane*8) = o;
}

// ---------------- layernorm fp32 -> bf16 (1 wave per block, 384 blocks) ----------------

__global__ __launch_bounds__(64) void k_lnb(const float* __restrict__ x, short* __restrict__ out,
    const float* __restrict__ g, const float* __restrict__ b)
{
  int lane = threadIdx.x;
  int row = blockIdx.x;
  const float* src = x + (size_t)row*512 + lane*8;
  float v[8];
  *(float4*)v = *(const float4*)src;
  *(float4*)(v+4) = *(const float4*)(src+4);
  float s = 0.f, ss = 0.f;
  #pragma unroll
  for (int e = 0; e < 8; ++e) { s += v[e]; ss += v[e]*v[e]; }
  #pragma unroll
  for (int m = 1; m < 64; m <<= 1) { s += __shfl_xor(s, m, 64); ss += __shfl_xor(ss, m, 64); }
  float mean = s * (1.f/512.f);
  float rs = rsqrtf(ss*(1.f/512.f) - mean*mean + 1e-5f);
  int c = lane * 8;
  short8 o;
  #pragma unroll
  for (int e = 0; e < 8; ++e) o[e] = f2b((v[e]-mean)*rs*g[c+e] + b[c+e]);
  *(short8*)(out + (size_t)row*512 + c) = o;
}

// ---------------- fused attention (round-10 proven) + XCD b-grouping swizzle ----------------

__global__ __launch_bounds__(256) void k_attn(
    const float* __restrict__ qparts, const short* __restrict__ kv,
    float* __restrict__ pvp, float* __restrict__ denp, float* __restrict__ aout)
{
  __shared__ float qs[12][512];
  __shared__ float ksh[128][65];
  __shared__ float dots[96][132];
  const int t = threadIdx.x;
  const int orig = blockIdx.x;
  const int wgid = (orig & 7) * 32 + (orig >> 3);
  const int b = wgid >> 3, jt = wgid & 7;

  for (int i = t; i < 6144; i += 256) {
    int s = i >> 9, d = i & 511;
    size_t o = (size_t)(b*12+s)*512 + d;
    qs[s][d] = qparts[o] + qparts[196608 + o] + qparts[393216 + o] + qparts[589824 + o];
  }

  const int jj = t & 127, sg = t >> 7;
  for (int h = 0; h < 8; ++h) {
    __syncthreads();
    #pragma unroll
    for (int i = 0; i < 4; ++i) {
      int c = i*256 + t;
      int j2 = c >> 3, seg = (c & 7) * 8;
      short8 raw = *(const short8*)(kv + ((size_t)(b*1024 + jt*128 + j2))*1024 + h*64 + seg);
      #pragma unroll
      for (int e = 0; e < 8; ++e) ksh[j2][seg+e] = b2f(raw[e]);
    }
    __syncthreads();
    float d6[6] = {};
    for (int d = 0; d < 64; ++d) {
      float kvv = ksh[jj][d];
      #pragma unroll
      for (int i = 0; i < 6; ++i) d6[i] += qs[sg*6+i][h*64+d] * kvv;
    }
    #pragma unroll
    for (int i = 0; i < 6; ++i) dots[(sg*6+i)*8 + h][jj] = d6[i] * 0.125f;
  }
  __syncthreads();

  {
    int j = t >> 1, half = (t & 1) * 48;
    float mx = -1e30f;
    #pragma unroll
    for (int i = 0; i < 48; ++i) mx = fmaxf(mx, dots[half+i][j]);
    mx = fmaxf(mx, __shfl_xor(mx, 1, 64));
    float ex[48];
    float sum = 0.f;
    #pragma unroll
    for (int i = 0; i < 48; ++i) { ex[i] = __expf(dots[half+i][j] - mx); sum += ex[i]; }
    sum += __shfl_xor(sum, 1, 64);
    float inv = 1.f / sum;
    float as_[6] = {0,0,0,0,0,0};
    #pragma unroll
    for (int i = 0; i < 48; ++i) {
      float a = ex[i] * inv;
      dots[half+i][j] = a;
      as_[i >> 3] += a;
    }
    if (aout) {
      int sbase = (t & 1) * 6;
      #pragma unroll
      for (int q2 = 0; q2 < 6; ++q2) {
        int s = sbase + q2;
        if (s < 8) aout[((size_t)(b*8+s))*1024 + jt*128 + j] = as_[q2] * 0.125f;
      }
    }
  }

  const int d = t & 63, sq = t >> 6;
  for (int h = 0; h < 8; ++h) {
    __syncthreads();
    #pragma unroll
    for (int i = 0; i < 4; ++i) {
      int c = i*256 + t;
      int j2 = c >> 3, seg = (c & 7) * 8;
      short8 raw = *(const short8*)(kv + ((size_t)(b*1024 + jt*128 + j2))*1024 + 512 + h*64 + seg);
      #pragma unroll
      for (int e = 0; e < 8; ++e) ksh[j2][seg+e] = b2f(raw[e]);
    }
    __syncthreads();
    float a3[3] = {0.f, 0.f, 0.f};
    for (int j2 = 0; j2 < 128; ++j2) {
      float vv = ksh[j2][d];
      #pragma unroll
      for (int i = 0; i < 3; ++i) a3[i] += dots[(sq + 4*i)*8 + h][j2] * vv;
    }
    #pragma unroll
    for (int i = 0; i < 3; ++i)
      pvp[((size_t)(jt*32+b))*6144 + (sq + 4*i)*512 + h*64 + d] = a3[i];
    if (t < 12) {
      float ls = 0.f;
      for (int j2 = 0; j2 < 128; ++j2) ls += dots[t*8 + h][j2];
      denp[((size_t)(jt*32+b))*96 + t*8 + h] = ls;
    }
  }
}

// pv reduce: grid (chunk=8, b=32) = 256 blocks; each sums 8 jt-partials for 768 i's.

__global__ __launch_bounds__(256) void k_pvred(const float* __restrict__ pvp, const float* __restrict__ denp,
                                               short* __restrict__ gruA)
{
  __shared__ float den[96];
  int t = threadIdx.x, chunk = blockIdx.x, b = blockIdx.y;
  if (t < 96) {
    float s = 0.f;
    #pragma unroll
    for (int jt2 = 0; jt2 < 8; ++jt2) s += denp[((size_t)(jt2*32+b))*96 + t];
    den[t] = s + 1e-8f;
  }
  __syncthreads();
  int i = chunk*768 + t;
  #pragma unroll
  for (int k = 0; k < 3; ++k, i += 256) {
    int s = i >> 9, rem = i & 511, h = rem >> 6;
    float acc = 0.f;
    #pragma unroll
    for (int jt2 = 0; jt2 < 8; ++jt2) acc += pvp[((size_t)(jt2*32+b))*6144 + i];
    gruA[((size_t)(b*12+s))*1024 + rem] = f2b(acc / den[s*8 + h]);
  }
}

// ---------------- selector head ----------------

__global__ __launch_bounds__(64) void k_decide(const float* __restrict__ hid, const float* __restrict__ w2,
    const float* __restrict__ b2, const float* __restrict__ slots, float* __restrict__ out)
{
  __shared__ float lg[16];
  __shared__ float dec[8];
  int b = blockIdx.x, t = threadIdx.x;
  if (t < 16) {
    int s = t >> 1, cl = t & 1;
    const float* hr = hid + (size_t)(b*12+s)*256;
    float a = b2[cl];
    for (int k = 0; k < 256; ++k) a += hr[k] * w2[k*2+cl];
    lg[t] = a;
  }
  __syncthreads();
  if (t == 0) {
    float d0[8]; float tot = 0.f;
    #pragma unroll
    for (int s = 0; s < 8; ++s) { d0[s] = (lg[2*s+1] > lg[2*s]) ? 1.f : 0.f; tot += d0[s]; }
    float needed = fmaxf(0.f, 2.f - tot);
    float cum = 0.f;
    #pragma unroll
    for (int s = 0; s < 8; ++s) {
      cum += 1.f - d0[s];
      float add = (d0[s] == 0.f && cum <= needed) ? 1.f : 0.f;
      float dd = d0[s] + add;
      dec[s] = dd;
      out[131072 + b*8 + s] = dd;
    }
  }
  __syncthreads();
  for (int i = 0; i < 64; ++i) {
    int idx = i*64 + t;
    int s = idx >> 9, c = idx & 511;
    out[(size_t)(b*8+s)*512 + c] = slots[(size_t)(b*12+s)*512 + c] * dec[s];
  }
}

// ---------------- host ----------------

extern "C" void kernel_launch(void* const* d_in, const int* in_sizes, int n_in,
                              void* d_out, int out_size, void* d_ws, size_t ws_size,
                              hipStream_t stream) {
  const float* features = (const float*)d_in[0];
  const float* noise    = (const float*)d_in[1];
  const float* w_in     = (const float*)d_in[2];
  const float* b_in     = (const float*)d_in[3];
  const float* ln1_g    = (const float*)d_in[4];
  const float* ln1_b    = (const float*)d_in[5];
  const float* slot_mu  = (const float*)d_in[6];
  const float* slot_ls  = (const float*)d_in[7];
  const float* wq       = (const float*)d_in[8];
  const float* wk       = (const float*)d_in[9];
  const float* wv       = (const float*)d_in[10];
  const float* gru_wih  = (const float*)d_in[11];
  const float* gru_whh  = (const float*)d_in[12];
  const float* gru_bih  = (const float*)d_in[13];
  const float* gru_bhh  = (const float*)d_in[14];
  const float* nslots_g = (const float*)d_in[15];
  const float* nslots_b = (const float*)d_in[16];
  const float* ninput_g = (const float*)d_in[17];
  const float* ninput_b = (const float*)d_in[18];
  const float* ffnln_g  = (const float*)d_in[19];
  const float* ffnln_b  = (const float*)d_in[20];
  const float* ffn_w1   = (const float*)d_in[21];
  const float* ffn_b1   = (const float*)d_in[22];
  const float* ffn_w2   = (const float*)d_in[23];
  const float* ffn_b2   = (const float*)d_in[24];
  const float* sel_w1   = (const float*)d_in[25];
  const float* sel_b1   = (const float*)d_in[26];
  const float* sel_w2   = (const float*)d_in[27];
  const float* sel_b2   = (const float*)d_in[28];
  float* out = (float*)d_out;
  float* fnull = (float*)nullptr;
  short* snull = (short*)nullptr;

  char* w = (char*)d_ws;
  size_t off = 0;
  auto alloc = [&](size_t n) { char* p = w + off; off = (off + n + 255) & ~255ULL; return p; };
  short* Abf   = (short*)alloc(75497472);   // features bf16 (32768x1152); reused as kv
  short* kv    = Abf;                       // (32768x1024) bf16, written after Abf dead
  short* ybf   = (short*)alloc(33554432);   // gemm1 out bf16
  short* inp   = (short*)alloc(33554432);   // LN'd input bf16
  short* Bt1   = (short*)alloc(1179648);
  short* Btkv  = (short*)alloc(1048576);
  short* wq_t  = (short*)alloc(524288);
  short* wgru  = (short*)alloc(4194304);
  float* gbias = (float*)alloc(8192);
  short* w1_t  = (short*)alloc(2097152);
  short* w2_t  = (short*)alloc(2097152);
  short* sl1_t = (short*)alloc(262144);
  float* slots = (float*)alloc(786432);
  short* gruA  = (short*)alloc(786432);
  short* sn    = (short*)alloc(393216);
  float* parts = (float*)alloc(12582912);
  float* pvp   = (float*)alloc(6291456);
  float* denp  = (float*)alloc(98304);
  short* fln   = (short*)alloc(393216);
  short* f1    = (short*)alloc(1572864);
  float* hid   = (float*)alloc(393216);
  (void)ws_size; (void)in_sizes; (void)n_in; (void)out_size;

  k_prep<<<dim3(20600), dim3(256), 0, stream>>>(
      w_in, wk, wv, wq, gru_wih, gru_whh, gru_bih, gru_bhh,
      ffn_w1, ffn_w2, sel_w1, slot_mu, slot_ls, noise, features,
      Bt1, Btkv, wq_t, wgru, gbias, w1_t, w2_t, sl1_t, slots, gruA, Abf);

  // phase A: y = features @ w_in + b_in ; inp = LN2(LN1(y)) ; kv = inp @ [wk|wv]
  gemm_p<<<dim3(1024), dim3(256), 0, stream>>>(Abf, Bt1, b_in, ybf, 512, 1152, 1152, 1152);
  k_ln2<<<dim3(8192), dim3(256), 0, stream>>>(ybf, inp, ln1_g, ln1_b, ninput_g, ninput_b);
  gemm_p<<<dim3(2048), dim3(256), 0, stream>>>(inp, Btkv, fnull, kv, 1024, 512, 512, 512);

  k_lnb<<<dim3(384), dim3(64), 0, stream>>>(slots, sn, nslots_g, nslots_b);  // iter-0 sn

  for (int it = 0; it < 3; ++it) {
    gemm_t<0,false,true><<<dim3(12, 4), dim3(256), 0, stream>>>(
        sn, wq_t, fnull, parts, snull, 512, 128, 512, 512, 512, 0, 0, 196608);
    k_attn<<<dim3(256), dim3(256), 0, stream>>>(parts, kv, pvp, denp,
        it == 2 ? out + 131328 : fnull);
    k_pvred<<<dim3(8, 32), dim3(256), 0, stream>>>(pvp, denp, gruA);
    gemm_t<0,false,true><<<dim3(48, 2), dim3(256), 0, stream>>>(
        gruA, wgru, fnull, parts, snull, 2048, 512, 1024, 1024, 2048, 0, 0, 786432);
    k_gruln<<<dim3(384), dim3(64), 0, stream>>>(parts, gbias, slots, fln, ffnln_g, ffnln_b);
    gemm_t<1,true,false><<<dim3(48), dim3(256), 0, stream>>>(
        fln, w1_t, ffn_b1, fnull, f1, 2048, 512, 512, 512, 2048, 2048, 0, 0);
    gemm_t<0,false,true><<<dim3(12, 4), dim3(256), 0, stream>>>(
        f1, w2_t, fnull, parts, snull, 512, 512, 2048, 2048, 512, 0, 0, 196608);
    k_ffn2redln<<<dim3(384), dim3(64), 0, stream>>>(parts, ffn_b2, slots, gruA, sn,
        nslots_g, nslots_b);
  }

  gemm_t<2,false,false><<<dim3(6), dim3(256), 0, stream>>>(
      gruA + 512, sl1_t, sel_b1, hid, snull, 256, 512, 1024, 512, 256, 0, 0, 0);
  k_decide<<<dim3(32), dim3(64), 0, stream>>>(hid, sel_w2, sel_b2, slots, out);
}

// Round 16
// 478.864 us; speedup vs baseline: 1.1071x; 1.1071x over previous
//
#include <hip/hip_runtime.h>
#include <math.h>

typedef __attribute__((ext_vector_type(8))) short short8;
typedef __attribute__((ext_vector_type(4))) float f32x4;

typedef const __attribute__((address_space(1))) void gv_t;
typedef __attribute__((address_space(3))) void lv_t;

__device__ __forceinline__ float b2f(short u) {
  union { unsigned int i; float f; } c; c.i = ((unsigned int)(unsigned short)u) << 16; return c.f;
}
__device__ __forceinline__ short f2b(float f) {
  union { float f; unsigned int i; } c; c.f = f;
  unsigned int r = c.i + 0x7FFFu + ((c.i >> 16) & 1u);
  return (short)(r >> 16);
}
__device__ __forceinline__ void glds(const short* g, short* l) {
  __builtin_amdgcn_global_load_lds((gv_t*)g, (lv_t*)l, 16, 0, 0);
}

// ---------------- prep: LDS-tiled transposes + gbias + slots init + features->bf16 ----------------
// blocks: [0,1392) transpose tiles | [1392,1400) gbias | [1400,2168) slots init |
// [2168,20600) features fp32->bf16

__global__ __launch_bounds__(256) void k_prep(
    const float* __restrict__ w_in, const float* __restrict__ wk, const float* __restrict__ wv,
    const float* __restrict__ wq, const float* __restrict__ wih, const float* __restrict__ whh,
    const float* __restrict__ bih, const float* __restrict__ bhh,
    const float* __restrict__ w1, const float* __restrict__ w2, const float* __restrict__ sl1,
    const float* __restrict__ mu, const float* __restrict__ lsig, const float* __restrict__ noise,
    const float* __restrict__ features,
    short* __restrict__ Bt1, short* __restrict__ Btkv, short* __restrict__ wq_t,
    short* __restrict__ wgru, float* __restrict__ gbias,
    short* __restrict__ w1_t, short* __restrict__ w2_t, short* __restrict__ sl1_t,
    float* __restrict__ slots, short* __restrict__ gruA, short* __restrict__ Abf)
{
  int blk = blockIdx.x, t = threadIdx.x;
  if (blk >= 2168) {           // features fp32 -> bf16, 8 elems/thread, coalesced
    int idx = (blk-2168)*256 + t;
    const float4* p = (const float4*)(features + (size_t)idx * 8);
    float4 a = p[0], b = p[1];
    short8 r;
    r[0]=f2b(a.x); r[1]=f2b(a.y); r[2]=f2b(a.z); r[3]=f2b(a.w);
    r[4]=f2b(b.x); r[5]=f2b(b.y); r[6]=f2b(b.z); r[7]=f2b(b.w);
    *(short8*)(Abf + (size_t)idx*8) = r;
  } else if (blk < 1392) {
    __shared__ float tile[64][68];
    int id = blk;
    const float* src = nullptr; short* dst; int Kd, n0, k0, sld = 0, sr0 = 0, sc0 = 0;
    if (id < 144) {            // w_in (1152x512) -> Bt1 (512x1152)
      dst = Bt1; Kd = 1152; n0 = (id/18)*64; k0 = (id%18)*64;
      src = w_in; sld = 512; sr0 = k0; sc0 = n0;
    } else if (id < 272) {     // [wk|wv] -> Btkv (1024x512)
      id -= 144; dst = Btkv; Kd = 512; n0 = (id/8)*64; k0 = (id%8)*64;
      src = (n0 < 512) ? wk : wv; sld = 512; sr0 = k0; sc0 = n0 & 511;
    } else if (id < 336) {     // wq (512x512) -> wq_t
      id -= 272; dst = wq_t; Kd = 512; n0 = (id/8)*64; k0 = (id%8)*64;
      src = wq; sld = 512; sr0 = k0; sc0 = n0;
    } else if (id < 848) {     // combined GRU (2048x1024): [r|z|xn|hn]
      id -= 336; dst = wgru; Kd = 1024; n0 = (id/16)*64; k0 = (id%16)*64;
      int g = n0 >> 9, c0 = n0 & 511; bool hi = (k0 >= 512);
      sld = 1536; sr0 = hi ? k0 - 512 : k0;
      if (g == 0)      { src = hi ? whh : wih; sc0 = c0; }
      else if (g == 1) { src = hi ? whh : wih; sc0 = 512 + c0; }
      else if (g == 2) { src = hi ? nullptr : wih; sc0 = 1024 + c0; }
      else             { src = hi ? whh : nullptr; sc0 = 1024 + c0; }
    } else if (id < 1104) {    // ffn_w1 (512x2048) -> w1_t (2048x512)
      id -= 848; dst = w1_t; Kd = 512; n0 = (id/8)*64; k0 = (id%8)*64;
      src = w1; sld = 2048; sr0 = k0; sc0 = n0;
    } else if (id < 1360) {    // ffn_w2 (2048x512) -> w2_t (512x2048)
      id -= 1104; dst = w2_t; Kd = 2048; n0 = (id/32)*64; k0 = (id%32)*64;
      src = w2; sld = 512; sr0 = k0; sc0 = n0;
    } else {                   // sel_w1 (512x256) -> sl1_t (256x512)
      id -= 1360; dst = sl1_t; Kd = 512; n0 = (id/8)*64; k0 = (id%8)*64;
      src = sl1; sld = 256; sr0 = k0; sc0 = n0;
    }
    if (src) {
      #pragma unroll
      for (int i = 0; i < 4; ++i) {
        int kk = (t >> 4) + i*16, nn = (t & 15) * 4;
        *(float4*)&tile[kk][nn] = *(const float4*)(src + (size_t)(sr0+kk)*sld + sc0 + nn);
      }
    } else {
      #pragma unroll
      for (int i = 0; i < 4; ++i) {
        int kk = (t >> 4) + i*16, nn = (t & 15) * 4;
        tile[kk][nn] = 0.f; tile[kk][nn+1] = 0.f; tile[kk][nn+2] = 0.f; tile[kk][nn+3] = 0.f;
      }
    }
    __syncthreads();
    #pragma unroll
    for (int i = 0; i < 2; ++i) {
      int c = i*256 + t;
      int row = c >> 3, off = (c & 7) * 8;
      short8 o;
      #pragma unroll
      for (int e = 0; e < 8; ++e) o[e] = f2b(tile[off+e][row]);
      *(short8*)(dst + (size_t)(n0+row)*Kd + k0 + off) = o;
    }
  } else if (blk < 1400) {     // combined GRU bias (2048)
    int n = (blk-1392)*256 + t;
    int g = n >> 9;
    float v;
    if (g <= 1)      v = bih[n] + bhh[n];
    else if (g == 2) v = bih[n];
    else             v = bhh[1024 + (n - 1536)];
    gbias[n] = v;
  } else {                     // slots init (fp32 + bf16 into gruA 2nd half)
    int idx = (blk-1400)*256 + t;
    int sd = idx % 6144;
    float v = mu[sd] + __expf(lsig[sd]) * noise[idx];
    slots[idx] = v;
    int row = idx >> 9, c = idx & 511;
    gruA[(size_t)row*1024 + 512 + c] = f2b(v);
  }
}

// ---------------- big-GEMM bf16: dbuf + counted-vmcnt pipeline (round-6 proven) ----------------

__global__ __launch_bounds__(256) void gemm_p(
    const short* __restrict__ A, const short* __restrict__ Bt,
    const float* __restrict__ bias, short* __restrict__ Cb,
    int N, int K, int lda, int ldb)
{
  __shared__ short As[2][128*64];
  __shared__ short Bs[2][128*64];
  const int t = threadIdx.x;
  const int lane = t & 63, wave = t >> 6;

  const int nwg = gridDim.x, gridX = N >> 7, orig = blockIdx.x;
  const int q = nwg >> 3, r = nwg & 7, xcd = orig & 7, base = orig >> 3;
  const int wgid = (xcd < r ? xcd*(q+1) : r*(q+1) + (xcd - r)*q) + base;
  const int bx = wgid % gridX, by = wgid / gridX;

  const int rowBase = by * 128, colBase = bx * 128;
  const int wm = (wave >> 1) * 64, wn = (wave & 1) * 64;
  const int fr = lane & 15, kcf = lane >> 4;
  f32x4 acc[4][4] = {};

  int srow[4], scol[4];
  #pragma unroll
  for (int i = 0; i < 4; ++i) {
    int c = i*256 + t;
    srow[i] = c >> 3;
    scol[i] = ((c & 7) ^ (srow[i] & 7)) * 8;
  }

  const int nsteps = K >> 6;
  auto STAGE = [&](int step, int buf) {
    int kb = step * 64;
    #pragma unroll
    for (int i = 0; i < 4; ++i) {
      int c = i*256 + t;
      glds(A + (size_t)(rowBase + srow[i])*lda + kb + scol[i], As[buf] + c*8);
      glds(Bt + (size_t)(colBase + srow[i])*ldb + kb + scol[i], Bs[buf] + c*8);
    }
  };

  STAGE(0, 0);
  if (nsteps > 1) { STAGE(1, 1); asm volatile("s_waitcnt vmcnt(8)" ::: "memory"); }
  else            {              asm volatile("s_waitcnt vmcnt(0)" ::: "memory"); }
  __builtin_amdgcn_sched_barrier(0);
  __builtin_amdgcn_s_barrier();
  __builtin_amdgcn_sched_barrier(0);

  for (int tt = 0; tt < nsteps; ++tt) {
    const int cur = tt & 1;
    short8 af[2][4], bf[2][4];
    #pragma unroll
    for (int ks = 0; ks < 2; ++ks) {
      int kc = ks*4 + kcf;
      #pragma unroll
      for (int m = 0; m < 4; ++m) {
        int rowa = wm + m*16 + fr;
        af[ks][m] = *(const short8*)(As[cur] + rowa*64 + (kc ^ (rowa & 7))*8);
        int rowb = wn + m*16 + fr;
        bf[ks][m] = *(const short8*)(Bs[cur] + rowb*64 + (kc ^ (rowb & 7))*8);
      }
    }
    asm volatile("s_waitcnt lgkmcnt(0)" ::: "memory");
    __builtin_amdgcn_sched_barrier(0);
    __builtin_amdgcn_s_barrier();
    __builtin_amdgcn_sched_barrier(0);
    if (tt + 2 < nsteps) STAGE(tt + 2, cur);
    #pragma unroll
    for (int ks = 0; ks < 2; ++ks)
      #pragma unroll
      for (int m = 0; m < 4; ++m)
        #pragma unroll
        for (int n = 0; n < 4; ++n)
          acc[m][n] = __builtin_amdgcn_mfma_f32_16x16x32_bf16(af[ks][m], bf[ks][n], acc[m][n], 0, 0, 0);
    if (tt + 1 < nsteps) {
      if (tt + 2 < nsteps) asm volatile("s_waitcnt vmcnt(8)" ::: "memory");
      else                 asm volatile("s_waitcnt vmcnt(0)" ::: "memory");
      __builtin_amdgcn_sched_barrier(0);
      __builtin_amdgcn_s_barrier();
      __builtin_amdgcn_sched_barrier(0);
    }
  }

  const int cr = (lane >> 4) * 4, cc2 = lane & 15;
  #pragma unroll
  for (int m = 0; m < 4; ++m)
    #pragma unroll
    for (int n = 0; n < 4; ++n) {
      int col = colBase + wn + n*16 + cc2;
      float bv = bias ? bias[col] : 0.f;
      #pragma unroll
      for (int j = 0; j < 4; ++j) {
        int row = rowBase + wm + m*16 + cr + j;
        Cb[(size_t)row*N + col] = f2b(acc[m][n][j] + bv);
      }
    }
}

// ---------------- small-GEMM: dbuf counted-vmcnt pipeline, split-K capable ----------------

template<int ACT, bool OUTBF, bool SPLITK>
__global__ __launch_bounds__(256) void gemm_t(
    const short* __restrict__ A, const short* __restrict__ Bt,
    const float* __restrict__ bias,
    float* __restrict__ Cf, short* __restrict__ Cb,
    int N, int Kp, int lda, int ldb, int ldf, int ldcb, int cboff, int skstride)
{
  __shared__ short As[2][128*64];
  __shared__ short Bs[2][128*64];
  const int t = threadIdx.x;
  const int lane = t & 63, wave = t >> 6;

  const int nwg = gridDim.x, gridX = N >> 7, orig = blockIdx.x;
  const int q = nwg >> 3, r = nwg & 7, xcd = orig & 7, base = orig >> 3;
  const int wgid = (xcd < r ? xcd*(q+1) : r*(q+1) + (xcd - r)*q) + base;
  const int bx = wgid % gridX, by = wgid / gridX;

  const int rowBase = by * 128, colBase = bx * 128;
  const size_t koff = (size_t)blockIdx.y * Kp;
  const int wm = (wave >> 1) * 64, wn = (wave & 1) * 64;
  const int fr = lane & 15, kcf = lane >> 4;
  f32x4 acc[4][4] = {};

  int srow[4], scol[4];
  #pragma unroll
  for (int i = 0; i < 4; ++i) {
    int c = i*256 + t;
    srow[i] = c >> 3;
    scol[i] = ((c & 7) ^ (srow[i] & 7)) * 8;
  }

  const int nsteps = Kp >> 6;
  auto STAGE = [&](int step, int buf) {
    int kb = step * 64;
    #pragma unroll
    for (int i = 0; i < 4; ++i) {
      int c = i*256 + t;
      glds(A + (size_t)(rowBase + srow[i])*lda + koff + kb + scol[i], As[buf] + c*8);
      glds(Bt + (size_t)(colBase + srow[i])*ldb + koff + kb + scol[i], Bs[buf] + c*8);
    }
  };

  STAGE(0, 0);
  if (nsteps > 1) { STAGE(1, 1); asm volatile("s_waitcnt vmcnt(8)" ::: "memory"); }
  else            {              asm volatile("s_waitcnt vmcnt(0)" ::: "memory"); }
  __builtin_amdgcn_sched_barrier(0);
  __builtin_amdgcn_s_barrier();
  __builtin_amdgcn_sched_barrier(0);

  for (int tt = 0; tt < nsteps; ++tt) {
    const int cur = tt & 1;
    short8 af[2][4], bf[2][4];
    #pragma unroll
    for (int ks = 0; ks < 2; ++ks) {
      int kc = ks*4 + kcf;
      #pragma unroll
      for (int m = 0; m < 4; ++m) {
        int rowa = wm + m*16 + fr;
        af[ks][m] = *(const short8*)(As[cur] + rowa*64 + (kc ^ (rowa & 7))*8);
        int rowb = wn + m*16 + fr;
        bf[ks][m] = *(const short8*)(Bs[cur] + rowb*64 + (kc ^ (rowb & 7))*8);
      }
    }
    asm volatile("s_waitcnt lgkmcnt(0)" ::: "memory");
    __builtin_amdgcn_sched_barrier(0);
    __builtin_amdgcn_s_barrier();
    __builtin_amdgcn_sched_barrier(0);
    if (tt + 2 < nsteps) STAGE(tt + 2, cur);
    #pragma unroll
    for (int ks = 0; ks < 2; ++ks)
      #pragma unroll
      for (int m = 0; m < 4; ++m)
        #pragma unroll
        for (int n = 0; n < 4; ++n)
          acc[m][n] = __builtin_amdgcn_mfma_f32_16x16x32_bf16(af[ks][m], bf[ks][n], acc[m][n], 0, 0, 0);
    if (tt + 1 < nsteps) {
      if (tt + 2 < nsteps) asm volatile("s_waitcnt vmcnt(8)" ::: "memory");
      else                 asm volatile("s_waitcnt vmcnt(0)" ::: "memory");
      __builtin_amdgcn_sched_barrier(0);
      __builtin_amdgcn_s_barrier();
      __builtin_amdgcn_sched_barrier(0);
    }
  }

  const int cr = (lane >> 4) * 4, cc2 = lane & 15;
  if (SPLITK) {
    float* dst = Cf + (size_t)blockIdx.y * skstride;
    #pragma unroll
    for (int m = 0; m < 4; ++m)
      #pragma unroll
      for (int n = 0; n < 4; ++n) {
        int col = colBase + wn + n*16 + cc2;
        #pragma unroll
        for (int j = 0; j < 4; ++j) {
          int row = rowBase + wm + m*16 + cr + j;
          dst[(size_t)row * ldf + col] = acc[m][n][j];
        }
      }
  } else {
    #pragma unroll
    for (int m = 0; m < 4; ++m)
      #pragma unroll
      for (int n = 0; n < 4; ++n) {
        int col = colBase + wn + n*16 + cc2;
        float bv = bias ? bias[col] : 0.f;
        #pragma unroll
        for (int j = 0; j < 4; ++j) {
          int row = rowBase + wm + m*16 + cr + j;
          float v = acc[m][n][j] + bv;
          if (ACT == 1) v = 0.5f*v*(1.f + erff(v*0.70710678118f));
          else if (ACT == 2) v = fmaxf(v, 0.f);
          if (OUTBF) Cb[(size_t)row*ldcb + cboff + col] = f2b(v);
          else Cf[(size_t)row*ldf + col] = v;
        }
      }
  }
}

// ---------------- GRU reduce (4 partials) + combine + fused ffn-LN (1 wave/block) ----------------

__global__ __launch_bounds__(64) void k_gruln(const float* __restrict__ p, const float* __restrict__ gbias,
    float* __restrict__ slots, short* __restrict__ fln,
    const float* __restrict__ g, const float* __restrict__ bb)
{
  int lane = threadIdx.x;
  int row = blockIdx.x;                  // 384 blocks
  int c = lane * 8;
  float g0[8], g1[8], g2[8], g3[8];
  *(float4*)g0     = *(const float4*)(gbias + c);
  *(float4*)(g0+4) = *(const float4*)(gbias + c + 4);
  *(float4*)g1     = *(const float4*)(gbias + 512 + c);
  *(float4*)(g1+4) = *(const float4*)(gbias + 512 + c + 4);
  *(float4*)g2     = *(const float4*)(gbias + 1024 + c);
  *(float4*)(g2+4) = *(const float4*)(gbias + 1024 + c + 4);
  *(float4*)g3     = *(const float4*)(gbias + 1536 + c);
  *(float4*)(g3+4) = *(const float4*)(gbias + 1536 + c + 4);
  const float* base = p + (size_t)row*2048 + c;
  #pragma unroll
  for (int s = 0; s < 4; ++s) {
    const float* qq = base + (size_t)s*786432;
    #pragma unroll
    for (int gi = 0; gi < 4; ++gi) {
      float* dst = (gi == 0) ? g0 : (gi == 1) ? g1 : (gi == 2) ? g2 : g3;
      float4 a = *(const float4*)(qq + gi*512), b4 = *(const float4*)(qq + gi*512 + 4);
      dst[0]+=a.x; dst[1]+=a.y; dst[2]+=a.z; dst[3]+=a.w;
      dst[4]+=b4.x; dst[5]+=b4.y; dst[6]+=b4.z; dst[7]+=b4.w;
    }
  }
  float hold[8], v[8];
  *(float4*)hold     = *(const float4*)(slots + (size_t)row*512 + c);
  *(float4*)(hold+4) = *(const float4*)(slots + (size_t)row*512 + c + 4);
  #pragma unroll
  for (int e = 0; e < 8; ++e) {
    float r = 1.f/(1.f+__expf(-g0[e]));
    float z = 1.f/(1.f+__expf(-g1[e]));
    float n = tanhf(g2[e] + r*g3[e]);
    v[e] = (1.f-z)*n + z*hold[e];
  }
  *(float4*)(slots + (size_t)row*512 + c)     = *(float4*)v;
  *(float4*)(slots + (size_t)row*512 + c + 4) = *(float4*)(v+4);
  float s1 = 0.f, s2 = 0.f;
  #pragma unroll
  for (int e = 0; e < 8; ++e) { s1 += v[e]; s2 += v[e]*v[e]; }
  #pragma unroll
  for (int m = 1; m < 64; m <<= 1) { s1 += __shfl_xor(s1, m, 64); s2 += __shfl_xor(s2, m, 64); }
  float mean = s1 * (1.f/512.f);
  float rs = rsqrtf(s2*(1.f/512.f) - mean*mean + 1e-5f);
  short8 o;
  #pragma unroll
  for (int e = 0; e < 8; ++e) o[e] = f2b((v[e]-mean)*rs*g[c+e] + bb[c+e]);
  *(short8*)(fln + (size_t)row*512 + c) = o;
}

// ---------------- ffn2 reduce (8 partials) + residual + fused nslots-LN (1 wave/block) ----------------

__global__ __launch_bounds__(64) void k_ffn2redln(const float* __restrict__ p, const float* __restrict__ b2,
    float* __restrict__ slots, short* __restrict__ gruA, short* __restrict__ sn,
    const float* __restrict__ g, const float* __restrict__ bb)
{
  int lane = threadIdx.x;
  int row = blockIdx.x;                  // 384 blocks
  int c = lane * 8;
  size_t base = (size_t)row*512 + c;
  float v[8];
  *(float4*)v     = *(const float4*)(slots + base);
  *(float4*)(v+4) = *(const float4*)(slots + base + 4);
  #pragma unroll
  for (int e = 0; e < 8; ++e) v[e] += b2[c+e];
  #pragma unroll
  for (int s = 0; s < 8; ++s) {
    const float* qq = p + (size_t)s*196608 + base;
    float4 a = *(const float4*)qq, b4 = *(const float4*)(qq+4);
    v[0]+=a.x; v[1]+=a.y; v[2]+=a.z; v[3]+=a.w;
    v[4]+=b4.x; v[5]+=b4.y; v[6]+=b4.z; v[7]+=b4.w;
  }
  *(float4*)(slots + base)     = *(float4*)v;
  *(float4*)(slots + base + 4) = *(float4*)(v+4);
  short8 o;
  #pragma unroll
  for (int e = 0; e < 8; ++e) o[e] = f2b(v[e]);
  *(short8*)(gruA + (size_t)row*1024 + 512 + c) = o;
  float s1 = 0.f, s2 = 0.f;
  #pragma unroll
  for (int e = 0; e < 8; ++e) { s1 += v[e]; s2 += v[e]*v[e]; }
  #pragma unroll
  for (int m = 1; m < 64; m <<= 1) { s1 += __shfl_xor(s1, m, 64); s2 += __shfl_xor(s2, m, 64); }
  float mean = s1 * (1.f/512.f);
  float rs = rsqrtf(s2*(1.f/512.f) - mean*mean + 1e-5f);
  short8 o2;
  #pragma unroll
  for (int e = 0; e < 8; ++e) o2[e] = f2b((v[e]-mean)*rs*g[c+e] + bb[c+e]);
  *(short8*)(sn + base) = o2;
}

// ---------------- ffn1: sum 2 partials + bias, gelu, bf16 out ----------------

__global__ __launch_bounds__(256) void k_ffn1red(const float* __restrict__ p, const float* __restrict__ b1,
                                                 short* __restrict__ f1) {
  int i = blockIdx.x*256 + threadIdx.x; // 98304
  int col = (i*8) & 2047;
  float v[8], w[8];
  *(float4*)v = *(const float4*)(p + (size_t)i*8);
  *(float4*)(v+4) = *(const float4*)(p + (size_t)i*8 + 4);
  const float* p2 = p + 786432;
  *(float4*)w = *(const float4*)(p2 + (size_t)i*8);
  *(float4*)(w+4) = *(const float4*)(p2 + (size_t)i*8 + 4);
  short8 o;
  #pragma unroll
  for (int e = 0; e < 8; ++e) {
    float x = v[e] + w[e] + b1[col + e];
    x = 0.5f*x*(1.f + erff(x*0.70710678118f));
    o[e] = f2b(x);
  }
  *(short8*)(f1 + (size_t)i*8) = o;
}

// ---------------- double layernorm: inp = LN2(LN1(y)), bf16 in/out, wave per row ----------------

__global__ __launch_bounds__(256) void k_ln2(const short* __restrict__ y, short* __restrict__ inp,
    const float* __restrict__ g1, const float* __restrict__ b1,
    const float* __restrict__ g2, const float* __restrict__ b2)
{
  int t = threadIdx.x, lane = t & 63;
  int row = blockIdx.x * 4 + (t >> 6);
  const short8 raw = *(const short8*)(y + (size_t)row*512 + lane*8);
  float x[8];
  #pragma unroll
  for (int e = 0; e < 8; ++e) x[e] = b2f(raw[e]);
  float s = 0.f, ss = 0.f;
  #pragma unroll
  for (int e = 0; e < 8; ++e) { s += x[e]; ss += x[e]*x[e]; }
  #pragma unroll
  for (int m = 1; m < 64; m <<= 1) { s += __shfl_xor(s, m, 64); ss += __shfl_xor(ss, m, 64); }
  float mean = s * (1.f/512.f);
  float rs = rsqrtf(ss*(1.f/512.f) - mean*mean + 1e-5f);
  int c = lane * 8;
  #pragma unroll
  for (int e = 0; e < 8; ++e) x[e] = (x[e]-mean)*rs*g1[c+e] + b1[c+e];
  s = 0.f; ss = 0.f;
  #pragma unroll
  for (int e = 0; e < 8; ++e) { s += x[e]; ss += x[e]*x[e]; }
  #pragma unroll
  for (int m = 1; m < 64; m <<= 1) { s += __shfl_xor(s, m, 64); ss += __shfl_xor(ss, m, 64); }
  float mean2 = s * (1.f/512.f);
  float rs2 = rsqrtf(ss*(1.f/512.f) - mean2*mean2 + 1e-5f);
  short8 o;
  #pragma unroll
  for (int e = 0; e < 8; ++e) o[e] = f2b((x[e]-mean2)*rs2*g2[c+e] + b2[c+e]);
  *(short8*)(inp + (size_t)row*512 + lane*8) = o;
}

// ---------------- layernorm fp32 -> bf16 (1 wave per block, 384 blocks) ----------------

__global__ __launch_bounds__(64) void k_lnb(const float* __restrict__ x, short* __restrict__ out,
    const float* __restrict__ g, const float* __restrict__ b)
{
  int lane = threadIdx.x;
  int row = blockIdx.x;
  const float* src = x + (size_t)row*512 + lane*8;
  float v[8];
  *(float4*)v = *(const float4*)src;
  *(float4*)(v+4) = *(const float4*)(src+4);
  float s = 0.f, ss = 0.f;
  #pragma unroll
  for (int e = 0; e < 8; ++e) { s += v[e]; ss += v[e]*v[e]; }
  #pragma unroll
  for (int m = 1; m < 64; m <<= 1) { s += __shfl_xor(s, m, 64); ss += __shfl_xor(ss, m, 64); }
  float mean = s * (1.f/512.f);
  float rs = rsqrtf(ss*(1.f/512.f) - mean*mean + 1e-5f);
  int c = lane * 8;
  short8 o;
  #pragma unroll
  for (int e = 0; e < 8; ++e) o[e] = f2b((v[e]-mean)*rs*g[c+e] + b[c+e]);
  *(short8*)(out + (size_t)row*512 + c) = o;
}

// ---------------- fused attention (round-10 proven) + XCD b-grouping swizzle ----------------

__global__ __launch_bounds__(256) void k_attn(
    const float* __restrict__ qparts, const short* __restrict__ kv,
    float* __restrict__ pvp, float* __restrict__ denp, float* __restrict__ aout)
{
  __shared__ float qs[12][512];
  __shared__ float ksh[128][65];
  __shared__ float dots[96][132];
  const int t = threadIdx.x;
  const int orig = blockIdx.x;
  const int wgid = (orig & 7) * 32 + (orig >> 3);
  const int b = wgid >> 3, jt = wgid & 7;

  for (int i = t; i < 6144; i += 256) {
    int s = i >> 9, d = i & 511;
    size_t o = (size_t)(b*12+s)*512 + d;
    qs[s][d] = qparts[o] + qparts[196608 + o] + qparts[393216 + o] + qparts[589824 + o];
  }

  const int jj = t & 127, sg = t >> 7;
  for (int h = 0; h < 8; ++h) {
    __syncthreads();
    #pragma unroll
    for (int i = 0; i < 4; ++i) {
      int c = i*256 + t;
      int j2 = c >> 3, seg = (c & 7) * 8;
      short8 raw = *(const short8*)(kv + ((size_t)(b*1024 + jt*128 + j2))*1024 + h*64 + seg);
      #pragma unroll
      for (int e = 0; e < 8; ++e) ksh[j2][seg+e] = b2f(raw[e]);
    }
    __syncthreads();
    float d6[6] = {};
    for (int d = 0; d < 64; ++d) {
      float kvv = ksh[jj][d];
      #pragma unroll
      for (int i = 0; i < 6; ++i) d6[i] += qs[sg*6+i][h*64+d] * kvv;
    }
    #pragma unroll
    for (int i = 0; i < 6; ++i) dots[(sg*6+i)*8 + h][jj] = d6[i] * 0.125f;
  }
  __syncthreads();

  {
    int j = t >> 1, half = (t & 1) * 48;
    float mx = -1e30f;
    #pragma unroll
    for (int i = 0; i < 48; ++i) mx = fmaxf(mx, dots[half+i][j]);
    mx = fmaxf(mx, __shfl_xor(mx, 1, 64));
    float ex[48];
    float sum = 0.f;
    #pragma unroll
    for (int i = 0; i < 48; ++i) { ex[i] = __expf(dots[half+i][j] - mx); sum += ex[i]; }
    sum += __shfl_xor(sum, 1, 64);
    float inv = 1.f / sum;
    float as_[6] = {0,0,0,0,0,0};
    #pragma unroll
    for (int i = 0; i < 48; ++i) {
      float a = ex[i] * inv;
      dots[half+i][j] = a;
      as_[i >> 3] += a;
    }
    if (aout) {
      int sbase = (t & 1) * 6;
      #pragma unroll
      for (int q2 = 0; q2 < 6; ++q2) {
        int s = sbase + q2;
        if (s < 8) aout[((size_t)(b*8+s))*1024 + jt*128 + j] = as_[q2] * 0.125f;
      }
    }
  }

  const int d = t & 63, sq = t >> 6;
  for (int h = 0; h < 8; ++h) {
    __syncthreads();
    #pragma unroll
    for (int i = 0; i < 4; ++i) {
      int c = i*256 + t;
      int j2 = c >> 3, seg = (c & 7) * 8;
      short8 raw = *(const short8*)(kv + ((size_t)(b*1024 + jt*128 + j2))*1024 + 512 + h*64 + seg);
      #pragma unroll
      for (int e = 0; e < 8; ++e) ksh[j2][seg+e] = b2f(raw[e]);
    }
    __syncthreads();
    float a3[3] = {0.f, 0.f, 0.f};
    for (int j2 = 0; j2 < 128; ++j2) {
      float vv = ksh[j2][d];
      #pragma unroll
      for (int i = 0; i < 3; ++i) a3[i] += dots[(sq + 4*i)*8 + h][j2] * vv;
    }
    #pragma unroll
    for (int i = 0; i < 3; ++i)
      pvp[((size_t)(jt*32+b))*6144 + (sq + 4*i)*512 + h*64 + d] = a3[i];
    if (t < 12) {
      float ls = 0.f;
      for (int j2 = 0; j2 < 128; ++j2) ls += dots[t*8 + h][j2];
      denp[((size_t)(jt*32+b))*96 + t*8 + h] = ls;
    }
  }
}

// pv reduce: grid (chunk=8, b=32) = 256 blocks; each sums 8 jt-partials for 768 i's.

__global__ __launch_bounds__(256) void k_pvred(const float* __restrict__ pvp, const float* __restrict__ denp,
                                               short* __restrict__ gruA)
{
  __shared__ float den[96];
  int t = threadIdx.x, chunk = blockIdx.x, b = blockIdx.y;
  if (t < 96) {
    float s = 0.f;
    #pragma unroll
    for (int jt2 = 0; jt2 < 8; ++jt2) s += denp[((size_t)(jt2*32+b))*96 + t];
    den[t] = s + 1e-8f;
  }
  __syncthreads();
  int i = chunk*768 + t;
  #pragma unroll
  for (int k = 0; k < 3; ++k, i += 256) {
    int s = i >> 9, rem = i & 511, h = rem >> 6;
    float acc = 0.f;
    #pragma unroll
    for (int jt2 = 0; jt2 < 8; ++jt2) acc += pvp[((size_t)(jt2*32+b))*6144 + i];
    gruA[((size_t)(b*12+s))*1024 + rem] = f2b(acc / den[s*8 + h]);
  }
}

// ---------------- selector head ----------------

__global__ __launch_bounds__(64) void k_decide(const float* __restrict__ hid, const float* __restrict__ w2,
    const float* __restrict__ b2, const float* __restrict__ slots, float* __restrict__ out)
{
  __shared__ float lg[16];
  __shared__ float dec[8];
  int b = blockIdx.x, t = threadIdx.x;
  if (t < 16) {
    int s = t >> 1, cl = t & 1;
    const float* hr = hid + (size_t)(b*12+s)*256;
    float a = b2[cl];
    for (int k = 0; k < 256; ++k) a += hr[k] * w2[k*2+cl];
    lg[t] = a;
  }
  __syncthreads();
  if (t == 0) {
    float d0[8]; float tot = 0.f;
    #pragma unroll
    for (int s = 0; s < 8; ++s) { d0[s] = (lg[2*s+1] > lg[2*s]) ? 1.f : 0.f; tot += d0[s]; }
    float needed = fmaxf(0.f, 2.f - tot);
    float cum = 0.f;
    #pragma unroll
    for (int s = 0; s < 8; ++s) {
      cum += 1.f - d0[s];
      float add = (d0[s] == 0.f && cum <= needed) ? 1.f : 0.f;
      float dd = d0[s] + add;
      dec[s] = dd;
      out[131072 + b*8 + s] = dd;
    }
  }
  __syncthreads();
  for (int i = 0; i < 64; ++i) {
    int idx = i*64 + t;
    int s = idx >> 9, c = idx & 511;
    out[(size_t)(b*8+s)*512 + c] = slots[(size_t)(b*12+s)*512 + c] * dec[s];
  }
}

// ---------------- host ----------------

extern "C" void kernel_launch(void* const* d_in, const int* in_sizes, int n_in,
                              void* d_out, int out_size, void* d_ws, size_t ws_size,
                              hipStream_t stream) {
  const float* features = (const float*)d_in[0];
  const float* noise    = (const float*)d_in[1];
  const float* w_in     = (const float*)d_in[2];
  const float* b_in     = (const float*)d_in[3];
  const float* ln1_g    = (const float*)d_in[4];
  const float* ln1_b    = (const float*)d_in[5];
  const float* slot_mu  = (const float*)d_in[6];
  const float* slot_ls  = (const float*)d_in[7];
  const float* wq       = (const float*)d_in[8];
  const float* wk       = (const float*)d_in[9];
  const float* wv       = (const float*)d_in[10];
  const float* gru_wih  = (const float*)d_in[11];
  const float* gru_whh  = (const float*)d_in[12];
  const float* gru_bih  = (const float*)d_in[13];
  const float* gru_bhh  = (const float*)d_in[14];
  const float* nslots_g = (const float*)d_in[15];
  const float* nslots_b = (const float*)d_in[16];
  const float* ninput_g = (const float*)d_in[17];
  const float* ninput_b = (const float*)d_in[18];
  const float* ffnln_g  = (const float*)d_in[19];
  const float* ffnln_b  = (const float*)d_in[20];
  const float* ffn_w1   = (const float*)d_in[21];
  const float* ffn_b1   = (const float*)d_in[22];
  const float* ffn_w2   = (const float*)d_in[23];
  const float* ffn_b2   = (const float*)d_in[24];
  const float* sel_w1   = (const float*)d_in[25];
  const float* sel_b1   = (const float*)d_in[26];
  const float* sel_w2   = (const float*)d_in[27];
  const float* sel_b2   = (const float*)d_in[28];
  float* out = (float*)d_out;
  float* fnull = (float*)nullptr;
  short* snull = (short*)nullptr;

  char* w = (char*)d_ws;
  size_t off = 0;
  auto alloc = [&](size_t n) { char* p = w + off; off = (off + n + 255) & ~255ULL; return p; };
  short* Abf   = (short*)alloc(75497472);   // features bf16 (32768x1152); reused as kv
  short* kv    = Abf;                       // (32768x1024) bf16, written after Abf dead
  short* ybf   = (short*)alloc(33554432);   // gemm1 out bf16
  short* inp   = (short*)alloc(33554432);   // LN'd input bf16
  short* Bt1   = (short*)alloc(1179648);
  short* Btkv  = (short*)alloc(1048576);
  short* wq_t  = (short*)alloc(524288);
  short* wgru  = (short*)alloc(4194304);
  float* gbias = (float*)alloc(8192);
  short* w1_t  = (short*)alloc(2097152);
  short* w2_t  = (short*)alloc(2097152);
  short* sl1_t = (short*)alloc(262144);
  float* slots = (float*)alloc(786432);
  short* gruA  = (short*)alloc(786432);
  short* sn    = (short*)alloc(393216);
  float* parts = (float*)alloc(12582912);
  float* pvp   = (float*)alloc(6291456);
  float* denp  = (float*)alloc(98304);
  short* fln   = (short*)alloc(393216);
  short* f1    = (short*)alloc(1572864);
  float* hid   = (float*)alloc(393216);
  (void)ws_size; (void)in_sizes; (void)n_in; (void)out_size;

  k_prep<<<dim3(20600), dim3(256), 0, stream>>>(
      w_in, wk, wv, wq, gru_wih, gru_whh, gru_bih, gru_bhh,
      ffn_w1, ffn_w2, sel_w1, slot_mu, slot_ls, noise, features,
      Bt1, Btkv, wq_t, wgru, gbias, w1_t, w2_t, sl1_t, slots, gruA, Abf);

  // phase A: y = features @ w_in + b_in ; inp = LN2(LN1(y)) ; kv = inp @ [wk|wv]
  gemm_p<<<dim3(1024), dim3(256), 0, stream>>>(Abf, Bt1, b_in, ybf, 512, 1152, 1152, 1152);
  k_ln2<<<dim3(8192), dim3(256), 0, stream>>>(ybf, inp, ln1_g, ln1_b, ninput_g, ninput_b);
  gemm_p<<<dim3(2048), dim3(256), 0, stream>>>(inp, Btkv, fnull, kv, 1024, 512, 512, 512);

  k_lnb<<<dim3(384), dim3(64), 0, stream>>>(slots, sn, nslots_g, nslots_b);  // iter-0 sn

  for (int it = 0; it < 3; ++it) {
    gemm_t<0,false,true><<<dim3(12, 4), dim3(256), 0, stream>>>(
        sn, wq_t, fnull, parts, snull, 512, 128, 512, 512, 512, 0, 0, 196608);
    k_attn<<<dim3(256), dim3(256), 0, stream>>>(parts, kv, pvp, denp,
        it == 2 ? out + 131328 : fnull);
    k_pvred<<<dim3(8, 32), dim3(256), 0, stream>>>(pvp, denp, gruA);
    gemm_t<0,false,true><<<dim3(48, 4), dim3(256), 0, stream>>>(
        gruA, wgru, fnull, parts, snull, 2048, 256, 1024, 1024, 2048, 0, 0, 786432);
    k_gruln<<<dim3(384), dim3(64), 0, stream>>>(parts, gbias, slots, fln, ffnln_g, ffnln_b);
    gemm_t<0,false,true><<<dim3(48, 2), dim3(256), 0, stream>>>(
        fln, w1_t, fnull, parts, snull, 2048, 256, 512, 512, 2048, 0, 0, 786432);
    k_ffn1red<<<dim3(384), dim3(256), 0, stream>>>(parts, ffn_b1, f1);
    gemm_t<0,false,true><<<dim3(12, 8), dim3(256), 0, stream>>>(
        f1, w2_t, fnull, parts, snull, 512, 256, 2048, 2048, 512, 0, 0, 196608);
    k_ffn2redln<<<dim3(384), dim3(64), 0, stream>>>(parts, ffn_b2, slots, gruA, sn,
        nslots_g, nslots_b);
  }

  gemm_t<2,false,false><<<dim3(6), dim3(256), 0, stream>>>(
      gruA + 512, sl1_t, sel_b1, hid, snull, 256, 512, 1024, 512, 256, 0, 0, 0);
  k_decide<<<dim3(32), dim3(64), 0, stream>>>(hid, sel_w2, sel_b2, slots, out);
}